// Round 4
// baseline (276.361 us; speedup 1.0000x reference)
//
#include <hip/hip_runtime.h>

// HausdorffDTLoss: exact separable EDT (fg & bg) per image, then
// mean((pred-target)^2 * (pred_dt^2 + target_dt^2)).
// Envelope identity: g[i] = min_j f[j]+(i-j)^2 = i^2 + min_j (h[j]-2ij),
// h[j]=f[j]+j^2. All intermediates are integers, |val| < 2^17 -> u16 storage,
// fp32 math exact (R1-R12: absmax 0.0).
// R12 windowing: scan only |i-j| <= W, W = ceil(sqrt(max f over wave's
// outputs)) -- exact for any input (j=i always in-window; outside candidates
// have (i-j)^2 >= f(i) >= g(i), can only tie). 274 -> 188us.
//
// R13 vs R12 (zy 85us, VALUBusy 47%, Occupancy 36%): envelope is cheap now;
// the stall is stage-latency + barrier convoying at only 4 blocks/CU
// (512thr x 4 = 2048-thread cap). Restructure to 256-thread blocks, 8/CU:
//  - zy: z-half split, grid 2048 = (zh,pol,img,b,x); LDS 35.8 -> 18.9KB.
//    Stage reads the full z line (exact EDT needs it; duplicated across zh).
//    Writes g + x^2 (<= 65282, u16-exact) so xloss stage is a pure copy.
//  - xloss: i-round split, grid 2048 = (r,img,b,tile); one acc-pair live
//    (~48 VGPR), LDS 16.9KB, stage = pure u16 copy.
//  - __launch_bounds__(256,8) pins allocation to the 8-wave/SIMD budget.

constexpr int BIGI = 49153;      // 3*128^2+1, matches reference BIG exactly
constexpr int NVOX = 4194304;    // voxels per tensor (2 samples x 128^3)
constexpr int ST2  = 65;         // dword row stride: 65%32=1 -> 2-way max (free)

__global__ void zero_kernel(float* out, int* flags) {
    out[0] = 0.0f;
    flags[0] = 0; flags[1] = 0; flags[2] = 0; flags[3] = 0;
}

// Windowed 128-candidate lower-envelope accumulation into acc[16] at outputs
// i0..i0+15. p = column c of a [65*ST2] u32 LDS array of packed u16 h-values
// (row 64 = prefetch slack). Only pairs q in [qlo,qhi] (SGPR-uniform) are
// scanned; every candidate that can strictly win lies inside (R12 proof).
__device__ __forceinline__ void envelope_win(const unsigned int* __restrict__ p,
                                             const float i0f,
                                             const int qlo, const int qhi,
                                             float acc[16]) {
    unsigned int vc = p[qlo * ST2];
    float jm2 = -4.0f * (float)qlo;            // -2*(2q)
    for (int q = qlo; q <= qhi; ++q) {
        unsigned int vn = p[(q + 1) * ST2];    // 1-pair prefetch (slack row)
        float h0 = (float)(vc & 0xffffu);      // j = 2q
        float h1 = (float)(vc >> 16);          // j = 2q+1
        float jb = jm2 - 2.0f;
        float c0 = fmaf(jm2, i0f, h0);         // candidate at i = i0
        float c1 = fmaf(jb,  i0f, h1);
#pragma unroll
        for (int k = 0; k < 16; ++k) {
            acc[k] = fminf(acc[k], fminf(c0, c1));
            c0 += jm2; c1 += jb;               // exact: integers < 2^17
        }
        jm2 -= 4.0f;
        vc = vn;
    }
}

// Wave-uniform window W from the wave's 16 output rows' f-values
// (f = h - i^2), wave-maxed. Guarantees W*W >= fmax.
__device__ __forceinline__ int window_of(const unsigned int* __restrict__ p,
                                         const int i0) {
    int fmx = 0;
#pragma unroll
    for (int m = 0; m < 8; ++m) {
        unsigned int v = p[((i0 >> 1) + m) * ST2];
        int y0 = i0 + 2 * m, y1 = y0 + 1;
        int f0 = (int)(v & 0xffffu) - y0 * y0;
        int f1 = (int)(v >> 16) - y1 * y1;
        fmx = max(fmx, max(f0, f1));
    }
#pragma unroll
    for (int off = 32; off; off >>= 1) fmx = max(fmx, __shfl_xor(fmx, off));
    int W = (int)sqrtf((float)fmx);            // fmx <= 49153, exact in fp32
    W += (W * W < fmx);
    W += (W * W < fmx);                        // guarantees W*W >= fmx
    return W;
}

// Fused binarize + parallel bitmask z-EDT + windowed y-envelope for one
// z-half of one (b,x) slab, one image, one polarity. 256 thr, 18.9KB LDS,
// 8 blocks/CU. Grid 2048 = (zh, pol, img, b*x).
__global__ __launch_bounds__(256, 8) void zy_kernel(const float* __restrict__ pred,
                                                    const float* __restrict__ tgt,
                                                    unsigned short* __restrict__ ws,
                                                    int* __restrict__ flags) {
    __shared__ unsigned int hz[65 * ST2];          // packed u16 pairs: (y-pair, cz)
    __shared__ unsigned long long bm[256];         // site bitmasks: [y][z-half]
    const int t   = blockIdx.x;
    const int zh  = t & 1;                         // which z-half we OUTPUT
    const int pol = (t >> 1) & 1;                  // 0: fg EDT (sites=~fg), 1: bg
    const int img = (t >> 2) & 1;
    const int s   = t >> 3;                        // 0..255: b(2) x x(128)
    const int b   = s >> 7;
    const int x   = s & 127;
    const int sb  = (b * 128 + x) * 16384;         // + y*128 + z
    const int tid = threadIdx.x;
    const float* im = img ? tgt : pred;

    // ---- stage: full slab read -> per-wave ballot -> site bitmasks ----
    // (full z line required for exact z-EDT; duplicated across zh blocks)
    bool anyfg = false;
#pragma unroll
    for (int k = 0; k < 64; ++k) {
        int l = tid + k * 256;
        float v = im[sb + l];
        bool fg = v > 0.5f;
        anyfg |= fg;
        bool site = pol ? fg : !fg;
        unsigned long long bal = __ballot(site);
        if ((tid & 63) == 0) bm[l >> 6] = bal;     // l>>6 uniform per wave
    }
    if (!pol && __ballot(anyfg) != 0ULL && (tid & 63) == 0)
        atomicOr(flags + img * 2 + b, 1);          // idempotent across zh
    __syncthreads();

    // ---- parallel z-EDT for our z-half (masks cover the full line) ----
    unsigned short* hu = (unsigned short*)hz;
    const int cz = tid & 63;
    const int z  = zh * 64 + cz;                   // zh block-uniform branch
#pragma unroll
    for (int k = 0; k < 32; ++k) {
        int y = (tid >> 6) + k * 4;
        unsigned long long m0 = bm[2 * y], m1 = bm[2 * y + 1];
        int d;
        if (z < 64) {
            unsigned long long lm = m0 << (63 - z);
            unsigned long long rm = m0 >> z;
            int dfwd = lm ? __builtin_clzll(lm) : 999;
            int db0  = rm ? __builtin_ctzll(rm) : 999;
            int db1  = (m1 ? __builtin_ctzll(m1) : 999) + (64 - z);
            d = min(dfwd, min(db0, db1));
        } else {
            int zz = z - 64;
            unsigned long long lm = m1 << (63 - zz);
            unsigned long long rm = m1 >> zz;
            int df1 = lm ? __builtin_clzll(lm) : 999;
            int df0 = (m0 ? __builtin_clzll(m0) : 999) + zz + 1;
            int dbw = rm ? __builtin_ctzll(rm) : 999;
            d = min(min(df1, df0), dbw);
        }
        int f = (d <= 127) ? d * d : BIGI;         // empty line -> BIG (exact)
        hu[((y >> 1) * ST2 + cz) * 2 + (y & 1)] = (unsigned short)(f + y * y);
    }
    __syncthreads();

    // ---- y-envelope: c = cz column, 4 groups x 2 rounds, store g + x^2 ----
    unsigned short* outv = ws + (size_t)(img * 2 + pol) * NVOX + sb;
    const int xsq = x * x;
#pragma clang loop unroll(disable)
    for (int r = 0; r < 2; ++r) {                  // one acc[16] live at a time
        const int i0 = (tid >> 6) * 16 + r * 64;   // wave-uniform
        const float i0f = (float)i0;
        const int W = window_of(hz + cz, i0);
        const int qlo = __builtin_amdgcn_readfirstlane(max(0, (i0 - W) >> 1));
        const int qhi = __builtin_amdgcn_readfirstlane(min(63, (i0 + 15 + W) >> 1));
        float acc[16];
#pragma unroll
        for (int k = 0; k < 16; ++k) acc[k] = 3.0e38f;
        envelope_win(hz + cz, i0f, qlo, qhi, acc);
#pragma unroll
        for (int k = 0; k < 16; ++k) {             // g + x^2 <= 65282: u16
            float iif = i0f + (float)k;
            outv[(i0 + k) * 128 + z] =
                (unsigned short)((unsigned int)fmaf(iif, iif, acc[k]) + xsq);
        }
    }
}

// Windowed x-envelope for A and B + fused loss partial for ONE i-round of one
// 64-column tile. 256 thr, 16.9KB LDS, 8 blocks/CU. Grid 2048 = (r,img,b,tile).
// Stage is a pure u16 copy (zy pre-added x^2 = j^2).
__global__ __launch_bounds__(256, 8) void xloss_kernel(const float* __restrict__ pred,
                                                       const float* __restrict__ tgt,
                                                       const unsigned short* __restrict__ ws,
                                                       const int* __restrict__ flags,
                                                       float* __restrict__ out) {
    __shared__ unsigned int hx[65 * ST2];
    __shared__ float red[4];
    const int t    = blockIdx.x;
    const int r    = t & 1;                    // which i-round (x-half)
    const int img  = (t >> 1) & 1;
    const int b    = (t >> 2) & 1;
    const int q0   = (t >> 3) * 64;            // (y,z) tile base, 0..16320
    const int base = b * 2097152 + q0;         // + x*16384 + c
    const int tid  = threadIdx.x;
    const int c    = tid & 63;
    const int i0   = (tid >> 6) * 16 + r * 64; // wave-uniform
    const float i0f = (float)i0;
    unsigned short* hu = (unsigned short*)hx;
    const unsigned short* A16 = ws + (size_t)(img * 2) * NVOX;
    const unsigned short* B16 = A16 + NVOX;
    float accA[16], accB[16];

    // ---- stage A (pure copy) + envelope A ----
#pragma unroll
    for (int k = 0; k < 32; ++k) {
        int l = tid + k * 256;
        int cc = l & 63, j = l >> 6;
        hu[((j >> 1) * ST2 + cc) * 2 + (j & 1)] = A16[base + j * 16384 + cc];
    }
    __syncthreads();
    {
        const int W = window_of(hx + c, i0);
        const int qlo = __builtin_amdgcn_readfirstlane(max(0, (i0 - W) >> 1));
        const int qhi = __builtin_amdgcn_readfirstlane(min(63, (i0 + 15 + W) >> 1));
#pragma unroll
        for (int k = 0; k < 16; ++k) accA[k] = 3.0e38f;
        envelope_win(hx + c, i0f, qlo, qhi, accA);
    }
    __syncthreads();

    // ---- stage B (pure copy) + envelope B ----
#pragma unroll
    for (int k = 0; k < 32; ++k) {
        int l = tid + k * 256;
        int cc = l & 63, j = l >> 6;
        hu[((j >> 1) * ST2 + cc) * 2 + (j & 1)] = B16[base + j * 16384 + cc];
    }
    __syncthreads();
    {
        const int W = window_of(hx + c, i0);
        const int qlo = __builtin_amdgcn_readfirstlane(max(0, (i0 - W) >> 1));
        const int qhi = __builtin_amdgcn_readfirstlane(min(63, (i0 + 15 + W) >> 1));
#pragma unroll
        for (int k = 0; k < 16; ++k) accB[k] = 3.0e38f;
        envelope_win(hx + c, i0f, qlo, qhi, accB);
    }

    // ---- loss partial: (p-t)^2 * (sqrt(gA)+sqrt(gB))^2 * guard ----
    float s = 0.0f;
#pragma unroll
    for (int k = 0; k < 16; ++k) {
        float iif = i0f + (float)k;
        float gA = fmaf(iif, iif, accA[k]);
        float gB = fmaf(iif, iif, accB[k]);
        int v = base + (i0 + k) * 16384 + c;     // coalesced across c per k
        float d = pred[v] - tgt[v];
        float fld = sqrtf(gA) + sqrtf(gB);
        s += d * d * fld * fld;
    }
    if (!flags[img * 2 + b]) s = 0.0f;
#pragma unroll
    for (int off = 32; off > 0; off >>= 1) s += __shfl_down(s, off);
    if ((tid & 63) == 0) red[tid >> 6] = s;
    __syncthreads();
    if (tid == 0) {
        float tot = red[0] + red[1] + red[2] + red[3];
        atomicAdd(out, tot * (1.0f / 4194304.0f));
    }
}

extern "C" void kernel_launch(void* const* d_in, const int* in_sizes, int n_in,
                              void* d_out, int out_size, void* d_ws, size_t ws_size,
                              hipStream_t stream) {
    const float* pred = (const float*)d_in[0];
    const float* tgt  = (const float*)d_in[1];
    float* out = (float*)d_out;
    unsigned short* ws16 = (unsigned short*)d_ws;  // 4 u16 volumes = 33.6 MB
    int* flags = (int*)(ws16 + 4 * (size_t)NVOX);  // [img0_b0, img0_b1, img1_b0, img1_b1]

    zero_kernel<<<1, 1, 0, stream>>>(out, flags);
    zy_kernel<<<dim3(2048), 256, 0, stream>>>(pred, tgt, ws16, flags);
    xloss_kernel<<<dim3(2048), 256, 0, stream>>>(pred, tgt, ws16, flags, out);
}

// Round 5
// 181.862 us; speedup vs baseline: 1.5196x; 1.5196x over previous
//
#include <hip/hip_runtime.h>

// HausdorffDTLoss: exact separable EDT (fg & bg) per image, then
// mean((pred-target)^2 * (pred_dt^2 + target_dt^2)).
// Envelope identity: g[i] = min_j f[j]+(i-j)^2 = i^2 + min_j (h[j]-2ij),
// h[j]=f[j]+j^2. All intermediates are integers, |val| < 2^17 -> u16 storage,
// fp32 math exact (R1-R13: absmax 0.0).
// R12 windowing: scan only |i-j| <= W, W = ceil(sqrt(max f over outputs)) --
// exact for any input (j=i in-window; outside candidates >= f(i) >= g(i)).
//
// R14. R13's __launch_bounds__(256,8) caused scratch spill (xloss VGPR=32,
// WRITE_SIZE 219MB on a kernel that writes ~nothing) and zy's z-half split
// doubled stage reads -> 276us. Revert to R12 structure and instead:
//  - zy (512thr, R12 shape): two-phase stage -- batch all 32 slab loads into
//    registers, THEN ballot. R12's VGPR=24 shows only a few loads were in
//    flight; batching overlaps the ~32 HBM latencies. ~56 VGPR, still 8
//    waves/SIMD. Outputs g + x^2 (<= 65282, u16-exact) so xloss stage is a
//    pure copy.
//  - xloss: 32-column tiles, 256 thr, grid 2048 = (img,b,512 tiles): 8
//    blocks/CU by LDS (8.6KB) and natural regs (~50; only one acc[16] live,
//    A reduced to sqrtA before staging B). No duplicated global reads.
//    Window bounds derive from the WAVE's 32-row range i0w=(tid>>6)*32
//    (per-thread i0=(tid>>5)*16 is NOT wave-uniform; superset window = exact).
//    NO min-wave coercion anywhere.

constexpr int BIGI = 49153;      // 3*128^2+1, matches reference BIG exactly
constexpr int NVOX = 4194304;    // voxels per tensor (2 samples x 128^3)
constexpr int STZ  = 129;        // zy dword row stride: 129%32=1 -> 2-way max (free)
constexpr int STX  = 33;         // xloss dword row stride: 33%32=1 -> same property

__global__ void zero_kernel(float* out, int* flags) {
    out[0] = 0.0f;
    flags[0] = 0; flags[1] = 0; flags[2] = 0; flags[3] = 0;
}

// Windowed lower-envelope accumulation into acc[16] at outputs i0..i0+15.
// p = column c of a [65*stride] u32 LDS array of packed u16 h-values
// (row 64 = prefetch slack). Only pairs q in [qlo,qhi] (SGPR-uniform) are
// scanned; every candidate that can strictly win lies inside (R12 proof;
// supersets are always exact).
__device__ __forceinline__ void envelope_win(const unsigned int* __restrict__ p,
                                             const int stride, const float i0f,
                                             const int qlo, const int qhi,
                                             float acc[16]) {
    unsigned int vc = p[qlo * stride];
    float jm2 = -4.0f * (float)qlo;            // -2*(2q)
    for (int q = qlo; q <= qhi; ++q) {
        unsigned int vn = p[(q + 1) * stride]; // 1-pair prefetch (slack row)
        float h0 = (float)(vc & 0xffffu);      // j = 2q
        float h1 = (float)(vc >> 16);          // j = 2q+1
        float jb = jm2 - 2.0f;
        float c0 = fmaf(jm2, i0f, h0);         // candidate at i = i0
        float c1 = fmaf(jb,  i0f, h1);
#pragma unroll
        for (int k = 0; k < 16; ++k) {
            acc[k] = fminf(acc[k], fminf(c0, c1));
            c0 += jm2; c1 += jb;               // exact: integers < 2^17
        }
        jm2 -= 4.0f;
        vc = vn;
    }
}

// Wave-uniform window W: max f over the rows sampled by ALL lanes of the wave
// (each lane samples its 16 rows i0..i0+15; f = h - i^2), wave-maxed.
// Guarantees W*W >= fmax.
__device__ __forceinline__ int window_of(const unsigned int* __restrict__ p,
                                         const int stride, const int i0) {
    int fmx = 0;
#pragma unroll
    for (int m = 0; m < 8; ++m) {
        unsigned int v = p[((i0 >> 1) + m) * stride];
        int y0 = i0 + 2 * m, y1 = y0 + 1;
        int f0 = (int)(v & 0xffffu) - y0 * y0;
        int f1 = (int)(v >> 16) - y1 * y1;
        fmx = max(fmx, max(f0, f1));
    }
#pragma unroll
    for (int off = 32; off; off >>= 1) fmx = max(fmx, __shfl_xor(fmx, off));
    int W = (int)sqrtf((float)fmx);            // fmx <= 49153, exact in fp32
    W += (W * W < fmx);
    W += (W * W < fmx);                        // guarantees W*W >= fmx
    return W;
}

// Fused binarize + parallel bitmask z-EDT + windowed y-envelope for one (b,x)
// slab of one image, one polarity. 512 thr, 35.8KB LDS, 4 blocks/CU
// (thread-capped). Grid 1024 = (pol, img, b*x).
__global__ __launch_bounds__(512) void zy_kernel(const float* __restrict__ pred,
                                                 const float* __restrict__ tgt,
                                                 unsigned short* __restrict__ ws,
                                                 int* __restrict__ flags) {
    __shared__ unsigned int hz[65 * STZ];          // packed u16 pairs: (y-pair, z)
    __shared__ unsigned long long bm[256];         // site bitmasks: [y][z-half]
    const int t   = blockIdx.x;
    const int pol = t & 1;                         // 0: fg EDT (sites=~fg), 1: bg
    const int img = (t >> 1) & 1;
    const int s   = t >> 2;                        // 0..255: b(2) x x(128)
    const int b   = s >> 7;
    const int x   = s & 127;
    const int sb  = (b * 128 + x) * 16384;         // + y*128 + z
    const int tid = threadIdx.x;
    const float* im = img ? tgt : pred;

    // ---- stage phase 1: batch ALL 32 slab loads into registers (ILP) ----
    float vreg[32];
#pragma unroll
    for (int k = 0; k < 32; ++k) vreg[k] = im[sb + tid + k * 512];

    // ---- stage phase 2: ballots -> site bitmasks ----
    bool anyfg = false;
#pragma unroll
    for (int k = 0; k < 32; ++k) {
        bool fg = vreg[k] > 0.5f;
        anyfg |= fg;
        bool site = pol ? fg : !fg;
        unsigned long long bal = __ballot(site);
        if ((tid & 63) == 0) bm[(tid + k * 512) >> 6] = bal; // uniform per wave
    }
    if (!pol && __ballot(anyfg) != 0ULL && (tid & 63) == 0)
        atomicOr(flags + img * 2 + b, 1);
    __syncthreads();

    // ---- parallel z-EDT: per-voxel nearest-site distance from the masks ----
    unsigned short* hu = (unsigned short*)hz;
    const int z = tid & 127;                       // fixed per thread, uniform/wave
#pragma unroll
    for (int k = 0; k < 32; ++k) {
        int y = (tid >> 7) + k * 4;
        unsigned long long m0 = bm[2 * y], m1 = bm[2 * y + 1];
        int d;
        if (z < 64) {
            unsigned long long lm = m0 << (63 - z);
            unsigned long long rm = m0 >> z;
            int dfwd = lm ? __builtin_clzll(lm) : 999;
            int db0  = rm ? __builtin_ctzll(rm) : 999;
            int db1  = (m1 ? __builtin_ctzll(m1) : 999) + (64 - z);
            d = min(dfwd, min(db0, db1));
        } else {
            int zz = z - 64;
            unsigned long long lm = m1 << (63 - zz);
            unsigned long long rm = m1 >> zz;
            int df1 = lm ? __builtin_clzll(lm) : 999;
            int df0 = (m0 ? __builtin_clzll(m0) : 999) + zz + 1;
            int dbw = rm ? __builtin_ctzll(rm) : 999;
            d = min(min(df1, df0), dbw);
        }
        int f = (d <= 127) ? d * d : BIGI;         // empty line -> BIG (exact)
        hu[((y >> 1) * STZ) * 2 + (y & 1) + 2 * z] = (unsigned short)(f + y * y);
    }
    __syncthreads();

    // ---- y-envelope: c = z column, 4 groups x 2 rounds; store g + x^2 ----
    unsigned short* outv = ws + (size_t)(img * 2 + pol) * NVOX + sb;
    const int c = tid & 127;
    const int xsq = x * x;
#pragma clang loop unroll(disable)
    for (int r = 0; r < 2; ++r) {                  // one acc[16] live at a time
        const int i0 = (tid >> 7) * 16 + r * 64;   // wave-uniform (tid>>7)
        const float i0f = (float)i0;
        const int W = window_of(hz + c, STZ, i0);
        const int qlo = __builtin_amdgcn_readfirstlane(max(0, (i0 - W) >> 1));
        const int qhi = __builtin_amdgcn_readfirstlane(min(63, (i0 + 15 + W) >> 1));
        float acc[16];
#pragma unroll
        for (int k = 0; k < 16; ++k) acc[k] = 3.0e38f;
        envelope_win(hz + c, STZ, i0f, qlo, qhi, acc);
#pragma unroll
        for (int k = 0; k < 16; ++k) {             // g + x^2 <= 65282: u16
            float iif = i0f + (float)k;
            outv[(i0 + k) * 128 + c] =
                (unsigned short)((unsigned int)fmaf(iif, iif, acc[k]) + xsq);
        }
    }
}

// Windowed x-envelope for A and B + fused loss partial. 32-column tiles:
// 256 thr, 8.6KB LDS, 8 blocks/CU, no duplicated global reads.
// Grid 2048 = (img, b, 512 tiles). Stage = pure u16 copy (zy pre-added x^2).
__global__ __launch_bounds__(256) void xloss_kernel(const float* __restrict__ pred,
                                                    const float* __restrict__ tgt,
                                                    const unsigned short* __restrict__ ws,
                                                    const int* __restrict__ flags,
                                                    float* __restrict__ out) {
    __shared__ unsigned int hx[65 * STX];
    __shared__ float red[4];
    const int t    = blockIdx.x;
    const int img  = t & 1;                    // adjacent blocks share pred/tgt
    const int b    = (t >> 1) & 1;
    const int q0   = (t >> 2) * 32;            // (y,z) tile base, 0..16352
    const int base = b * 2097152 + q0;         // + x*16384 + c
    const int tid  = threadIdx.x;
    const int c    = tid & 31;                 // column within tile
    const int i0   = (tid >> 5) * 16;          // per-thread (NOT wave-uniform)
    const int i0w  = (tid >> 6) * 32;          // wave-uniform 32-row base
    const float i0f = (float)i0;
    unsigned short* hu = (unsigned short*)hx;
    const unsigned short* A16 = ws + (size_t)(img * 2) * NVOX;
    const unsigned short* B16 = A16 + NVOX;
    float sA[16], accB[16];

    // ---- stage A (pure copy) + envelope A -> sqrt(gA) ----
#pragma unroll
    for (int k = 0; k < 16; ++k) {
        int l = tid + k * 256;
        int cc = l & 31, j = l >> 5;
        hu[((j >> 1) * STX + cc) * 2 + (j & 1)] = A16[base + j * 16384 + cc];
    }
    __syncthreads();
    {
        const int W = window_of(hx + c, STX, i0);   // wave-maxed over 32 rows
        const int qlo = __builtin_amdgcn_readfirstlane(max(0, (i0w - W) >> 1));
        const int qhi = __builtin_amdgcn_readfirstlane(min(63, (i0w + 31 + W) >> 1));
        float acc[16];
#pragma unroll
        for (int k = 0; k < 16; ++k) acc[k] = 3.0e38f;
        envelope_win(hx + c, STX, i0f, qlo, qhi, acc);
#pragma unroll
        for (int k = 0; k < 16; ++k) {
            float iif = i0f + (float)k;
            sA[k] = sqrtf(fmaf(iif, iif, acc[k]));
        }
    }
    __syncthreads();

    // ---- stage B (pure copy) + envelope B ----
#pragma unroll
    for (int k = 0; k < 16; ++k) {
        int l = tid + k * 256;
        int cc = l & 31, j = l >> 5;
        hu[((j >> 1) * STX + cc) * 2 + (j & 1)] = B16[base + j * 16384 + cc];
    }
    __syncthreads();
    {
        const int W = window_of(hx + c, STX, i0);
        const int qlo = __builtin_amdgcn_readfirstlane(max(0, (i0w - W) >> 1));
        const int qhi = __builtin_amdgcn_readfirstlane(min(63, (i0w + 31 + W) >> 1));
#pragma unroll
        for (int k = 0; k < 16; ++k) accB[k] = 3.0e38f;
        envelope_win(hx + c, STX, i0f, qlo, qhi, accB);
    }

    // ---- loss partial: (p-t)^2 * (sqrt(gA)+sqrt(gB))^2 * guard ----
    float s = 0.0f;
#pragma unroll
    for (int k = 0; k < 16; ++k) {
        float iif = i0f + (float)k;
        float gB = fmaf(iif, iif, accB[k]);
        int v = base + (i0 + k) * 16384 + c;     // 128B contiguous per half-wave
        float d = pred[v] - tgt[v];
        float fld = sA[k] + sqrtf(gB);
        s += d * d * fld * fld;
    }
    if (!flags[img * 2 + b]) s = 0.0f;
#pragma unroll
    for (int off = 32; off > 0; off >>= 1) s += __shfl_down(s, off);
    if ((tid & 63) == 0) red[tid >> 6] = s;
    __syncthreads();
    if (tid == 0) {
        float tot = red[0] + red[1] + red[2] + red[3];
        atomicAdd(out, tot * (1.0f / 4194304.0f));
    }
}

extern "C" void kernel_launch(void* const* d_in, const int* in_sizes, int n_in,
                              void* d_out, int out_size, void* d_ws, size_t ws_size,
                              hipStream_t stream) {
    const float* pred = (const float*)d_in[0];
    const float* tgt  = (const float*)d_in[1];
    float* out = (float*)d_out;
    unsigned short* ws16 = (unsigned short*)d_ws;  // 4 u16 volumes = 33.6 MB
    int* flags = (int*)(ws16 + 4 * (size_t)NVOX);  // [img0_b0, img0_b1, img1_b0, img1_b1]

    zero_kernel<<<1, 1, 0, stream>>>(out, flags);
    zy_kernel<<<dim3(1024), 512, 0, stream>>>(pred, tgt, ws16, flags);
    xloss_kernel<<<dim3(2048), 256, 0, stream>>>(pred, tgt, ws16, flags, out);
}